// Round 14
// baseline (309.724 us; speedup 1.0000x reference)
//
#include <hip/hip_runtime.h>
#include <hip/hip_fp16.h>
#include <math.h>

#define NN 100000
#define NE 1600000
#define INF_ 128
#define HID 64
#define NEG 0.2f
#define NBUK 196     // buckets of 512 dst nodes
#define ACH 2048     // edges per block in bucket-build phases

__device__ __forceinline__ float lrelu(float v){ return v > 0.f ? v : NEG*v; }

__device__ __forceinline__ float4 up4(uint2 v){
  half2* ph = (half2*)&v;
  float2 a = __half22float2(ph[0]);
  float2 b = __half22float2(ph[1]);
  return make_float4(a.x, a.y, b.x, b.y);
}
__device__ __forceinline__ uint2 pk4(float4 o){
  union { half2 h[2]; uint2 u; } pk;
  pk.h[0] = __floats2half2_rn(o.x, o.y);
  pk.h[1] = __floats2half2_rn(o.z, o.w);
  return pk.u;
}

// ---------------- CSR build: two-level LDS bucket sort (512-node buckets) -----

__global__ void k_zero_i(int* p, int n){
  int i = blockIdx.x*blockDim.x + threadIdx.x;
  if (i < n) p[i] = 0;
}

__global__ __launch_bounds__(256) void kA0(const int* __restrict__ dst,
                                           int* __restrict__ ghist){
  __shared__ int hist[NBUK];
  int t = threadIdx.x;
  if (t < NBUK) hist[t] = 0;
  __syncthreads();
  int eb = blockIdx.x*ACH;
  for (int i = t; i < ACH; i += 256){
    int e = eb + i;
    if (e < NE) atomicAdd(&hist[dst[e] >> 9], 1);
  }
  __syncthreads();
  if (t < NBUK && hist[t]) atomicAdd(&ghist[t], hist[t]);
}

__global__ __launch_bounds__(256) void k_scan_bk(const int* __restrict__ ghist,
                                                 int* __restrict__ bases,
                                                 int* __restrict__ cur,
                                                 int* __restrict__ off){
  __shared__ int l[256];
  int t = threadIdx.x;
  int v = (t < NBUK) ? ghist[t] : 0;
  l[t] = v; __syncthreads();
  for (int o = 1; o < 256; o <<= 1){
    int u = (t >= o) ? l[t-o] : 0;
    __syncthreads();
    l[t] += u;
    __syncthreads();
  }
  if (t < NBUK){ bases[t] = l[t] - v; cur[t] = l[t] - v; }
  if (t == 0){ bases[NBUK] = NE; off[NN] = NE; }
}

__global__ __launch_bounds__(256) void kA1(const int* __restrict__ src,
                                           const int* __restrict__ dst,
                                           int* cur,
                                           unsigned* __restrict__ bucketed){
  __shared__ unsigned pk[ACH];
  __shared__ unsigned char bk[ACH];
  __shared__ int hist[NBUK], base[NBUK];
  int t = threadIdx.x;
  if (t < NBUK) hist[t] = 0;
  __syncthreads();
  int eb = blockIdx.x*ACH;
  for (int i = t; i < ACH; i += 256){
    int e = eb + i;
    if (e < NE){
      int d = dst[e];
      int b = d >> 9;
      atomicAdd(&hist[b], 1);
      pk[i] = ((unsigned)src[e] << 9) | (unsigned)(d & 511);
      bk[i] = (unsigned char)b;
    } else bk[i] = 0xFF;
  }
  __syncthreads();
  if (t < NBUK){
    base[t] = hist[t] ? atomicAdd(&cur[t], hist[t]) : 0;
    hist[t] = 0;
  }
  __syncthreads();
  for (int i = t; i < ACH; i += 256){
    if (bk[i] != 0xFF){
      int b = bk[i];
      int slot = atomicAdd(&hist[b], 1);
      bucketed[base[b] + slot] = pk[i];
    }
  }
}

__global__ __launch_bounds__(256) void kB(const unsigned* __restrict__ bucketed,
                                          const int* __restrict__ bases,
                                          int* __restrict__ csr,
                                          int* __restrict__ off,
                                          int* __restrict__ cnt,
                                          float* __restrict__ dinv){
  __shared__ int lc[512];
  __shared__ int lcur[512];
  __shared__ int red[256];
  int b = blockIdx.x, t = threadIdx.x;
  int bbase = bases[b], bend = bases[b+1];
  lc[t] = 0; lc[t + 256] = 0;
  __syncthreads();
  for (int e = bbase + t; e < bend; e += 256)
    atomicAdd(&lc[bucketed[e] & 511], 1);
  __syncthreads();
  int a0 = lc[2*t], a1 = lc[2*t+1];
  int s = a0 + a1;
  red[t] = s;
  __syncthreads();
  for (int o = 1; o < 256; o <<= 1){
    int v = (t >= o) ? red[t-o] : 0;
    __syncthreads();
    red[t] += v;
    __syncthreads();
  }
  int e0 = red[t] - s;
  lcur[2*t]   = e0;
  lcur[2*t+1] = e0 + a0;
  int node = b*512 + 2*t;
  if (node < NN){
    off[node]  = bbase + e0;
    cnt[node]  = a0;
    dinv[node] = rsqrtf((float)a0 + 1.f);
  }
  if (node + 1 < NN){
    off[node+1]  = bbase + e0 + a0;
    cnt[node+1]  = a1;
    dinv[node+1] = rsqrtf((float)a1 + 1.f);
  }
  __syncthreads();
  for (int e = bbase + t; e < bend; e += 256){
    unsigned w = bucketed[e];
    int slot = atomicAdd(&lcur[w & 511], 1);
    csr[bbase + slot] = (int)(w >> 9);
  }
}

// ---------------- dense linears: fp16 in/out, f32 accumulate ----------------

__global__ __launch_bounds__(256, 4) void k_gemm_in(const float* __restrict__ x,
                                                    const float* __restrict__ w,
                                                    const float* __restrict__ dinv,
                                                    __half* __restrict__ hsH){
  __shared__ float xl[4][8][INF_];
  const int wave = threadIdx.x >> 6, lane = threadIdx.x & 63;
  int rb = blockIdx.x*32 + wave*8;
  if (rb >= NN) return;
  #pragma unroll
  for (int r = 0; r < 8; ++r){
    xl[wave][r][lane]      = x[(size_t)(rb+r)*INF_ + lane];
    xl[wave][r][lane + 64] = x[(size_t)(rb+r)*INF_ + lane + 64];
  }
  float acc[8] = {0.f,0.f,0.f,0.f,0.f,0.f,0.f,0.f};
  #pragma unroll
  for (int c = 0; c < 8; ++c){
    float wv[16];
    #pragma unroll
    for (int j = 0; j < 16; ++j) wv[j] = w[(c*16 + j)*HID + lane];
    #pragma unroll
    for (int r = 0; r < 8; ++r)
      #pragma unroll
      for (int j = 0; j < 16; ++j)
        acc[r] = fmaf(xl[wave][r][c*16 + j], wv[j], acc[r]);
  }
  #pragma unroll
  for (int r = 0; r < 8; ++r)
    hsH[(size_t)(rb+r)*HID + lane] = __float2half(acc[r]*dinv[rb+r]);
}

__global__ __launch_bounds__(256, 4) void k_gat_lin(const __half* __restrict__ h1H,
                                                    const float* __restrict__ w,
                                                    const float* __restrict__ atts,
                                                    const float* __restrict__ attd,
                                                    __half* __restrict__ h2preH,
                                                    float* __restrict__ as_,
                                                    float* __restrict__ ad_){
  __shared__ float xl[4][8][HID];
  __shared__ float asl[HID], adl[HID];
  if (threadIdx.x < HID){
    asl[threadIdx.x] = atts[threadIdx.x];
    adl[threadIdx.x] = attd[threadIdx.x];
  }
  __syncthreads();
  const int wave = threadIdx.x >> 6, lane = threadIdx.x & 63;
  int rb = blockIdx.x*32 + wave*8;
  if (rb >= NN) return;
  #pragma unroll
  for (int r = 0; r < 8; ++r)
    xl[wave][r][lane] = __half2float(h1H[(size_t)(rb+r)*HID + lane]);
  float acc[8] = {0.f,0.f,0.f,0.f,0.f,0.f,0.f,0.f};
  #pragma unroll
  for (int c = 0; c < 4; ++c){
    float wv[16];
    #pragma unroll
    for (int j = 0; j < 16; ++j) wv[j] = w[(c*16 + j)*HID + lane];
    #pragma unroll
    for (int r = 0; r < 8; ++r)
      #pragma unroll
      for (int j = 0; j < 16; ++j)
        acc[r] = fmaf(xl[wave][r][c*16 + j], wv[j], acc[r]);
  }
  #pragma unroll
  for (int r = 0; r < 8; ++r){
    h2preH[(size_t)(rb+r)*HID + lane] = __float2half(acc[r]);
    xl[wave][r][lane] = acc[r];
  }
  int rr = lane >> 3, t = lane & 7;
  float vs = 0.f, vd = 0.f;
  #pragma unroll
  for (int i = 0; i < 8; ++i){
    float v = xl[wave][rr][t + 8*i];
    vs = fmaf(v, asl[t + 8*i], vs);
    vd = fmaf(v, adl[t + 8*i], vd);
  }
  #pragma unroll
  for (int o = 1; o < 8; o <<= 1){
    vs += __shfl_xor(vs, o, 64);
    vd += __shfl_xor(vd, o, 64);
  }
  if (t == 0){ as_[rb + rr] = vs; ad_[rb + rr] = vd; }
}

template<int MF32>
__global__ __launch_bounds__(256, 4) void k_sage_dense(const __half* __restrict__ meanH,
                                                       const float* meanF,
                                                       const __half* __restrict__ h2H,
                                                       const float* __restrict__ wlh,
                                                       const float* __restrict__ wrh,
                                                       const float* __restrict__ b,
                                                       float* out){
  __shared__ float ml[4][8][HID];
  __shared__ float hl[4][8][HID];
  const int wave = threadIdx.x >> 6, lane = threadIdx.x & 63;
  int rb = blockIdx.x*32 + wave*8;
  if (rb >= NN) return;
  float bl = b[lane];
  #pragma unroll
  for (int r = 0; r < 8; ++r){
    if constexpr (MF32 == 1)
      ml[wave][r][lane] = meanF[(size_t)(rb+r)*HID + lane];
    else
      ml[wave][r][lane] = __half2float(meanH[(size_t)(rb+r)*HID + lane]);
    hl[wave][r][lane] = __half2float(h2H[(size_t)(rb+r)*HID + lane]);
  }
  float acc[8] = {bl,bl,bl,bl,bl,bl,bl,bl};
  #pragma unroll
  for (int c = 0; c < 4; ++c){
    float wvl[16], wvr[16];
    #pragma unroll
    for (int j = 0; j < 16; ++j){
      wvl[j] = wlh[(c*16 + j)*HID + lane];
      wvr[j] = wrh[(c*16 + j)*HID + lane];
    }
    #pragma unroll
    for (int r = 0; r < 8; ++r)
      #pragma unroll
      for (int j = 0; j < 16; ++j){
        acc[r] = fmaf(ml[wave][r][c*16 + j], wvl[j], acc[r]);
        acc[r] = fmaf(hl[wave][r][c*16 + j], wvr[j], acc[r]);
      }
  }
  #pragma unroll
  for (int r = 0; r < 8; ++r)
    out[(size_t)(rb+r)*HID + lane] = acc[r];
}

// ---------------- gathers: QUAD-NODE per wave, fp16 rows ----------------
// off[] = segment starts (NN+1). NN = 6250*16 exactly -> no node guards.
// 4 nodes/wave x 4 edge-slots = 16 rows in flight per lane per k-iter.

__device__ __forceinline__ void row_acc(const uint2* __restrict__ rh,
                                        size_t s, int f, float p, float4& acc){
  float4 r = up4(rh[s*16 + f]);
  acc.x = fmaf(r.x, p, acc.x); acc.y = fmaf(r.y, p, acc.y);
  acc.z = fmaf(r.z, p, acc.z); acc.w = fmaf(r.w, p, acc.w);
}

__device__ __forceinline__ float4 sel4(int q, float4 a0, float4 a1, float4 a2, float4 a3){
  return q==0 ? a0 : (q==1 ? a1 : (q==2 ? a2 : a3));
}

__global__ __launch_bounds__(256) void k_gcn_gather(const int* __restrict__ csr,
                                                    const int* __restrict__ off,
                                                    const uint2* __restrict__ hsH,
                                                    const float* __restrict__ dinv,
                                                    const float4* __restrict__ gcn_b4,
                                                    uint2* __restrict__ h1H){
  const int wave = threadIdx.x >> 6, lane = threadIdx.x & 63;
  int nb = blockIdx.x*16 + wave*4;
  int q = lane >> 4, f = lane & 15;
  int ofs[5];
  #pragma unroll
  for (int j = 0; j < 5; ++j) ofs[j] = off[nb + j];
  int cc[4], ee[4];
  #pragma unroll
  for (int j = 0; j < 4; ++j){ cc[j] = ofs[j]; ee[j] = ofs[j+1]; }
  float4 A[4] = {{0,0,0,0},{0,0,0,0},{0,0,0,0},{0,0,0,0}};
  bool more = (cc[0]<ee[0]) | (cc[1]<ee[1]) | (cc[2]<ee[2]) | (cc[3]<ee[3]);
  while (more){
    int idx[4], m[4];
    #pragma unroll
    for (int j = 0; j < 4; ++j){
      m[j] = ee[j] - cc[j]; if (m[j] > 64) m[j] = 64;
      idx[j] = (lane < m[j]) ? csr[cc[j] + lane] : 0;
    }
    int mm = max(max(m[0],m[1]), max(m[2],m[3]));
    for (int k = 0; k < mm; k += 16){
      int ka = k + q, kb = k + 4 + q, kc = k + 8 + q, kd = k + 12 + q;
      #pragma unroll
      for (int j = 0; j < 4; ++j){
        int sa = __shfl(idx[j], ka, 64);
        int sb = __shfl(idx[j], kb, 64);
        int sc = __shfl(idx[j], kc, 64);
        int sd = __shfl(idx[j], kd, 64);
        if (ka < m[j]) row_acc(hsH, (size_t)sa, f, 1.f, A[j]);
        if (kb < m[j]) row_acc(hsH, (size_t)sb, f, 1.f, A[j]);
        if (kc < m[j]) row_acc(hsH, (size_t)sc, f, 1.f, A[j]);
        if (kd < m[j]) row_acc(hsH, (size_t)sd, f, 1.f, A[j]);
      }
    }
    more = false;
    #pragma unroll
    for (int j = 0; j < 4; ++j){
      cc[j] += 64;
      if (cc[j] < ee[j]) more = true;
    }
  }
  #pragma unroll
  for (int o = 16; o <= 32; o <<= 1)
    #pragma unroll
    for (int j = 0; j < 4; ++j){
      A[j].x += __shfl_xor(A[j].x, o, 64);
      A[j].y += __shfl_xor(A[j].y, o, 64);
      A[j].z += __shfl_xor(A[j].z, o, 64);
      A[j].w += __shfl_xor(A[j].w, o, 64);
    }
  int node = nb + q;
  float4 Aq = sel4(q, A[0], A[1], A[2], A[3]);
  float4 s  = up4(hsH[(size_t)node*16 + f]);
  float  di = dinv[node];
  float4 b4 = gcn_b4[f];
  float4 o;
  o.x = fmaxf((Aq.x + s.x)*di + b4.x, 0.f);
  o.y = fmaxf((Aq.y + s.y)*di + b4.y, 0.f);
  o.z = fmaxf((Aq.z + s.z)*di + b4.z, 0.f);
  o.w = fmaxf((Aq.w + s.w)*di + b4.w, 0.f);
  h1H[(size_t)node*16 + f] = pk4(o);
}

__global__ __launch_bounds__(256) void k_gat_gather(const int* __restrict__ csr,
                                                    const int* __restrict__ off,
                                                    const float* __restrict__ as_,
                                                    const float* __restrict__ ad_,
                                                    const uint2* __restrict__ h2preH,
                                                    const float4* __restrict__ gat_b4,
                                                    uint2* __restrict__ h2H){
  const int wave = threadIdx.x >> 6, lane = threadIdx.x & 63;
  int nb = blockIdx.x*16 + wave*4;
  int q = lane >> 4, f = lane & 15;
  int ofs[5];
  #pragma unroll
  for (int j = 0; j < 5; ++j) ofs[j] = off[nb + j];
  int cc[4], ee[4];
  float adi[4], ps[4], S[4];
  float4 A[4] = {{0,0,0,0},{0,0,0,0},{0,0,0,0},{0,0,0,0}};
  #pragma unroll
  for (int j = 0; j < 4; ++j){
    cc[j] = ofs[j]; ee[j] = ofs[j+1];
    adi[j] = ad_[nb + j];
    ps[j]  = expf(fminf(lrelu(as_[nb + j] + adi[j]), 80.f));
    S[j] = 0.f;
  }
  bool more = (cc[0]<ee[0]) | (cc[1]<ee[1]) | (cc[2]<ee[2]) | (cc[3]<ee[3]);
  while (more){
    int idx[4], m[4];
    float pv[4];
    #pragma unroll
    for (int j = 0; j < 4; ++j){
      m[j] = ee[j] - cc[j]; if (m[j] > 64) m[j] = 64;
      idx[j] = 0; pv[j] = 0.f;
      if (lane < m[j]){
        idx[j] = csr[cc[j] + lane];
        pv[j]  = expf(fminf(lrelu(as_[idx[j]] + adi[j]), 80.f));
      }
    }
    int mm = max(max(m[0],m[1]), max(m[2],m[3]));
    for (int k = 0; k < mm; k += 16){
      int ka = k + q, kb = k + 4 + q, kc = k + 8 + q, kd = k + 12 + q;
      #pragma unroll
      for (int j = 0; j < 4; ++j){
        int sa = __shfl(idx[j], ka, 64); float wa = __shfl(pv[j], ka, 64);
        int sb = __shfl(idx[j], kb, 64); float wb = __shfl(pv[j], kb, 64);
        int sc = __shfl(idx[j], kc, 64); float wc = __shfl(pv[j], kc, 64);
        int sd = __shfl(idx[j], kd, 64); float wd = __shfl(pv[j], kd, 64);
        if (ka < m[j]){ row_acc(h2preH, (size_t)sa, f, wa, A[j]); S[j] += wa; }
        if (kb < m[j]){ row_acc(h2preH, (size_t)sb, f, wb, A[j]); S[j] += wb; }
        if (kc < m[j]){ row_acc(h2preH, (size_t)sc, f, wc, A[j]); S[j] += wc; }
        if (kd < m[j]){ row_acc(h2preH, (size_t)sd, f, wd, A[j]); S[j] += wd; }
      }
    }
    more = false;
    #pragma unroll
    for (int j = 0; j < 4; ++j){
      cc[j] += 64;
      if (cc[j] < ee[j]) more = true;
    }
  }
  #pragma unroll
  for (int o = 16; o <= 32; o <<= 1)
    #pragma unroll
    for (int j = 0; j < 4; ++j){
      A[j].x += __shfl_xor(A[j].x, o, 64);
      A[j].y += __shfl_xor(A[j].y, o, 64);
      A[j].z += __shfl_xor(A[j].z, o, 64);
      A[j].w += __shfl_xor(A[j].w, o, 64);
      S[j]   += __shfl_xor(S[j],   o, 64);
    }
  int node = nb + q;
  float4 Aq = sel4(q, A[0], A[1], A[2], A[3]);
  float Sq  = q==0 ? S[0] : (q==1 ? S[1] : (q==2 ? S[2] : S[3]));
  float psq = q==0 ? ps[0] : (q==1 ? ps[1] : (q==2 ? ps[2] : ps[3]));
  float inv = 1.f/(Sq + psq);
  float4 h0 = up4(h2preH[(size_t)node*16 + f]);
  float4 b4 = gat_b4[f];
  float4 o;
  o.x = fmaxf((Aq.x + h0.x*psq)*inv + b4.x, 0.f);
  o.y = fmaxf((Aq.y + h0.y*psq)*inv + b4.y, 0.f);
  o.z = fmaxf((Aq.z + h0.z*psq)*inv + b4.z, 0.f);
  o.w = fmaxf((Aq.w + h0.w*psq)*inv + b4.w, 0.f);
  h2H[(size_t)node*16 + f] = pk4(o);
}

template<int MF32>
__global__ __launch_bounds__(256) void k_sage_gather(const int* __restrict__ csr,
                                                     const int* __restrict__ off,
                                                     const int* __restrict__ cnt,
                                                     const uint2* __restrict__ h2H,
                                                     uint2* __restrict__ meanH,
                                                     float4* meanF){
  const int wave = threadIdx.x >> 6, lane = threadIdx.x & 63;
  int nb = blockIdx.x*16 + wave*4;
  int q = lane >> 4, f = lane & 15;
  int ofs[5];
  #pragma unroll
  for (int j = 0; j < 5; ++j) ofs[j] = off[nb + j];
  int cc[4], ee[4];
  #pragma unroll
  for (int j = 0; j < 4; ++j){ cc[j] = ofs[j]; ee[j] = ofs[j+1]; }
  float4 A[4] = {{0,0,0,0},{0,0,0,0},{0,0,0,0},{0,0,0,0}};
  bool more = (cc[0]<ee[0]) | (cc[1]<ee[1]) | (cc[2]<ee[2]) | (cc[3]<ee[3]);
  while (more){
    int idx[4], m[4];
    #pragma unroll
    for (int j = 0; j < 4; ++j){
      m[j] = ee[j] - cc[j]; if (m[j] > 64) m[j] = 64;
      idx[j] = (lane < m[j]) ? csr[cc[j] + lane] : 0;
    }
    int mm = max(max(m[0],m[1]), max(m[2],m[3]));
    for (int k = 0; k < mm; k += 16){
      int ka = k + q, kb = k + 4 + q, kc = k + 8 + q, kd = k + 12 + q;
      #pragma unroll
      for (int j = 0; j < 4; ++j){
        int sa = __shfl(idx[j], ka, 64);
        int sb = __shfl(idx[j], kb, 64);
        int sc = __shfl(idx[j], kc, 64);
        int sd = __shfl(idx[j], kd, 64);
        if (ka < m[j]) row_acc(h2H, (size_t)sa, f, 1.f, A[j]);
        if (kb < m[j]) row_acc(h2H, (size_t)sb, f, 1.f, A[j]);
        if (kc < m[j]) row_acc(h2H, (size_t)sc, f, 1.f, A[j]);
        if (kd < m[j]) row_acc(h2H, (size_t)sd, f, 1.f, A[j]);
      }
    }
    more = false;
    #pragma unroll
    for (int j = 0; j < 4; ++j){
      cc[j] += 64;
      if (cc[j] < ee[j]) more = true;
    }
  }
  #pragma unroll
  for (int o = 16; o <= 32; o <<= 1)
    #pragma unroll
    for (int j = 0; j < 4; ++j){
      A[j].x += __shfl_xor(A[j].x, o, 64);
      A[j].y += __shfl_xor(A[j].y, o, 64);
      A[j].z += __shfl_xor(A[j].z, o, 64);
      A[j].w += __shfl_xor(A[j].w, o, 64);
    }
  int node = nb + q;
  float4 Aq = sel4(q, A[0], A[1], A[2], A[3]);
  float inv = 1.f/fmaxf((float)cnt[node], 1.f);
  float4 o = {Aq.x*inv, Aq.y*inv, Aq.z*inv, Aq.w*inv};
  if constexpr (MF32 == 1) meanF[(size_t)node*16 + f] = o;
  else                     meanH[(size_t)node*16 + f] = pk4(o);
}

// ---------------- launch ----------------

extern "C" void kernel_launch(void* const* d_in, const int* in_sizes, int n_in,
                              void* d_out, int out_size, void* d_ws, size_t ws_size,
                              hipStream_t stream) {
  const float* x      = (const float*)d_in[0];
  const int*   ei     = (const int*)d_in[1];
  const int*   src    = ei;
  const int*   dstp   = ei + NE;
  const float* gcn_w  = (const float*)d_in[2];
  const float* gcn_b  = (const float*)d_in[3];
  const float* gat_w  = (const float*)d_in[4];
  const float* att_s  = (const float*)d_in[5];
  const float* att_d  = (const float*)d_in[6];
  const float* gat_b  = (const float*)d_in[7];
  const float* s_wl   = (const float*)d_in[8];
  const float* s_wr   = (const float*)d_in[9];
  const float* s_b    = (const float*)d_in[10];
  float* outp = (float*)d_out;

  // workspace layout (4-byte words)
  int*   ghist = (int*)d_ws;             // 256 (196 used)
  int*   bases = ghist + 256;            // 256 (197 used)
  int*   cur   = bases + 256;            // 256 (196 used)
  int*   cnt   = cur + 256;              // NN
  int*   off   = cnt + NN;               // NN+1 (+pad)
  float* dinv  = (float*)(off + NN + 8);
  float* as_   = dinv + NN;
  float* ad_   = as_  + NN;
  unsigned* bucketed = (unsigned*)(ad_ + NN);   // NE
  int*   csr   = (int*)(bucketed + NE);         // NE

  // fp16 planes: 256-byte aligned (round-12 lesson: misaligned 128B rows cost
  // +50% FETCH in the gathers)
  size_t hb_off = (((size_t)(char*)(csr + NE) - (size_t)(char*)d_ws) + 255) & ~(size_t)255;
  __half* HB0 = (__half*)((char*)d_ws + hb_off);
  __half* HB1 = HB0 + (size_t)NN*HID;

  const size_t NH = (size_t)NN*HID;
  size_t need  = hb_off + 2*NH*2;
  size_t need1 = hb_off + NH*2;

  const int B = 256;
  const int GROWS = (NN + 31)/32;
  const int GG4 = NN/16;                // quad-node gathers: 6250 blocks exact
  const int GA = (NE + ACH - 1)/ACH;

  // CSR build
  k_zero_i <<<1, 256, 0, stream>>>(ghist, NBUK);
  kA0      <<<GA, B, 0, stream>>>(dstp, ghist);
  k_scan_bk<<<1, 256, 0, stream>>>(ghist, bases, cur, off);
  kA1      <<<GA, B, 0, stream>>>(src, dstp, cur, bucketed);
  kB       <<<NBUK, 256, 0, stream>>>(bucketed, bases, csr, off, cnt, dinv);

  if (ws_size >= need){
    // buf0: hs -> h2pre -> mean ; buf1: h1 -> h2
    k_gemm_in   <<<GROWS, B, 0, stream>>>(x, gcn_w, dinv, HB0);
    k_gcn_gather<<<GG4, B, 0, stream>>>(csr, off, (const uint2*)HB0, dinv,
                                        (const float4*)gcn_b, (uint2*)HB1);
    k_gat_lin   <<<GROWS, B, 0, stream>>>(HB1, gat_w, att_s, att_d, HB0, as_, ad_);
    k_gat_gather<<<GG4, B, 0, stream>>>(csr, off, as_, ad_, (const uint2*)HB0,
                                        (const float4*)gat_b, (uint2*)HB1);
    k_sage_gather<0><<<GG4, B, 0, stream>>>(csr, off, cnt, (const uint2*)HB1,
                                            (uint2*)HB0, nullptr);
    k_sage_dense<0><<<GROWS, B, 0, stream>>>(HB0, nullptr, HB1,
                                             s_wl, s_wr, s_b, outp);
  } else {
    __half* F0 = (ws_size >= need1) ? (__half*)outp : HB0;
    __half* F1 = (ws_size >= need1) ? HB0 : (__half*)outp;
    k_gemm_in   <<<GROWS, B, 0, stream>>>(x, gcn_w, dinv, F0);
    k_gcn_gather<<<GG4, B, 0, stream>>>(csr, off, (const uint2*)F0, dinv,
                                        (const float4*)gcn_b, (uint2*)F1);
    k_gat_lin   <<<GROWS, B, 0, stream>>>(F1, gat_w, att_s, att_d, F0, as_, ad_);
    k_gat_gather<<<GG4, B, 0, stream>>>(csr, off, as_, ad_, (const uint2*)F0,
                                        (const float4*)gat_b, (uint2*)F1);
    k_sage_gather<1><<<GG4, B, 0, stream>>>(csr, off, cnt, (const uint2*)F1,
                                            nullptr, (float4*)outp);
    k_sage_dense<1><<<GROWS, B, 0, stream>>>(nullptr, outp, F1,
                                             s_wl, s_wr, s_b, outp);
  }
}

// Round 15
// 275.370 us; speedup vs baseline: 1.1248x; 1.1248x over previous
//
#include <hip/hip_runtime.h>
#include <hip/hip_fp16.h>
#include <math.h>

#define NN 100000
#define NE 1600000
#define INF_ 128
#define HID 64
#define NEG 0.2f
#define NBUK 196     // buckets of 512 dst nodes
#define CAP 10240    // fixed bucket capacity (mean 8192, sigma~90 -> +22 sigma)
#define ACH 2048     // edges per block in partition phase

__device__ __forceinline__ float lrelu(float v){ return v > 0.f ? v : NEG*v; }

__device__ __forceinline__ float4 up4(uint2 v){
  half2* ph = (half2*)&v;
  float2 a = __half22float2(ph[0]);
  float2 b = __half22float2(ph[1]);
  return make_float4(a.x, a.y, b.x, b.y);
}
__device__ __forceinline__ uint2 pk4(float4 o){
  union { half2 h[2]; uint2 u; } pk;
  pk.h[0] = __floats2half2_rn(o.x, o.y);
  pk.h[1] = __floats2half2_rn(o.z, o.w);
  return pk.u;
}

// ---------------- CSR build: fixed-capacity bucket sort (no pre-count) -------

__global__ void k_init_cur(int* cur){
  int t = threadIdx.x;
  if (t < NBUK) cur[t] = t*CAP;
}

// partition edges into fixed bucket regions; packed word (src<<9)|(d&511)
__global__ __launch_bounds__(256) void kA1(const int* __restrict__ src,
                                           const int* __restrict__ dst,
                                           int* cur,
                                           unsigned* __restrict__ bucketed){
  __shared__ unsigned pk[ACH];
  __shared__ unsigned char bk[ACH];
  __shared__ int hist[NBUK], base[NBUK];
  int t = threadIdx.x;
  if (t < NBUK) hist[t] = 0;
  __syncthreads();
  int eb = blockIdx.x*ACH;
  for (int i = t; i < ACH; i += 256){
    int e = eb + i;
    if (e < NE){
      int d = dst[e];
      int b = d >> 9;
      atomicAdd(&hist[b], 1);
      pk[i] = ((unsigned)src[e] << 9) | (unsigned)(d & 511);
      bk[i] = (unsigned char)b;
    } else bk[i] = 0xFF;
  }
  __syncthreads();
  if (t < NBUK){
    base[t] = hist[t] ? atomicAdd(&cur[t], hist[t]) : 0;
    hist[t] = 0;
  }
  __syncthreads();
  for (int i = t; i < ACH; i += 256){
    if (bk[i] != 0xFF){
      int b = bk[i];
      int slot = atomicAdd(&hist[b], 1);
      bucketed[base[b] + slot] = pk[i];
    }
  }
}

// per-bucket CSR finalize; bucket b region [b*CAP, cur[b])
__global__ __launch_bounds__(256) void kB(const unsigned* __restrict__ bucketed,
                                          const int* __restrict__ cur,
                                          int* __restrict__ csr,
                                          int* __restrict__ off,
                                          int* __restrict__ cnt,
                                          float* __restrict__ dinv){
  __shared__ int lc[512];
  __shared__ int lcur[512];
  __shared__ int red[256];
  int b = blockIdx.x, t = threadIdx.x;
  int bbase = b*CAP, bend = cur[b];
  lc[t] = 0; lc[t + 256] = 0;
  __syncthreads();
  for (int e = bbase + t; e < bend; e += 256)
    atomicAdd(&lc[bucketed[e] & 511], 1);
  __syncthreads();
  int a0 = lc[2*t], a1 = lc[2*t+1];
  int s = a0 + a1;
  red[t] = s;
  __syncthreads();
  for (int o = 1; o < 256; o <<= 1){
    int v = (t >= o) ? red[t-o] : 0;
    __syncthreads();
    red[t] += v;
    __syncthreads();
  }
  int e0 = red[t] - s;
  lcur[2*t]   = e0;
  lcur[2*t+1] = e0 + a0;
  int node = b*512 + 2*t;
  if (node < NN){
    off[node]  = bbase + e0;
    cnt[node]  = a0;
    dinv[node] = rsqrtf((float)a0 + 1.f);
  }
  if (node + 1 < NN){
    off[node+1]  = bbase + e0 + a0;
    cnt[node+1]  = a1;
    dinv[node+1] = rsqrtf((float)a1 + 1.f);
  }
  __syncthreads();
  for (int e = bbase + t; e < bend; e += 256){
    unsigned w = bucketed[e];
    int slot = atomicAdd(&lcur[w & 511], 1);
    csr[bbase + slot] = (int)(w >> 9);
  }
}

// ---------------- dense linears: fp16 in/out, f32 accumulate ----------------

__global__ __launch_bounds__(256, 4) void k_gemm_in(const float* __restrict__ x,
                                                    const float* __restrict__ w,
                                                    const float* __restrict__ dinv,
                                                    __half* __restrict__ hsH){
  __shared__ float xl[4][8][INF_];
  const int wave = threadIdx.x >> 6, lane = threadIdx.x & 63;
  int rb = blockIdx.x*32 + wave*8;
  if (rb >= NN) return;
  #pragma unroll
  for (int r = 0; r < 8; ++r){
    xl[wave][r][lane]      = x[(size_t)(rb+r)*INF_ + lane];
    xl[wave][r][lane + 64] = x[(size_t)(rb+r)*INF_ + lane + 64];
  }
  float acc[8] = {0.f,0.f,0.f,0.f,0.f,0.f,0.f,0.f};
  #pragma unroll
  for (int c = 0; c < 8; ++c){
    float wv[16];
    #pragma unroll
    for (int j = 0; j < 16; ++j) wv[j] = w[(c*16 + j)*HID + lane];
    #pragma unroll
    for (int r = 0; r < 8; ++r)
      #pragma unroll
      for (int j = 0; j < 16; ++j)
        acc[r] = fmaf(xl[wave][r][c*16 + j], wv[j], acc[r]);
  }
  #pragma unroll
  for (int r = 0; r < 8; ++r)
    hsH[(size_t)(rb+r)*HID + lane] = __float2half(acc[r]*dinv[rb+r]);
}

__global__ __launch_bounds__(256, 4) void k_gat_lin(const __half* __restrict__ h1H,
                                                    const float* __restrict__ w,
                                                    const float* __restrict__ atts,
                                                    const float* __restrict__ attd,
                                                    __half* __restrict__ h2preH,
                                                    float* __restrict__ as_,
                                                    float* __restrict__ ad_){
  __shared__ float xl[4][8][HID];
  __shared__ float asl[HID], adl[HID];
  if (threadIdx.x < HID){
    asl[threadIdx.x] = atts[threadIdx.x];
    adl[threadIdx.x] = attd[threadIdx.x];
  }
  __syncthreads();
  const int wave = threadIdx.x >> 6, lane = threadIdx.x & 63;
  int rb = blockIdx.x*32 + wave*8;
  if (rb >= NN) return;
  #pragma unroll
  for (int r = 0; r < 8; ++r)
    xl[wave][r][lane] = __half2float(h1H[(size_t)(rb+r)*HID + lane]);
  float acc[8] = {0.f,0.f,0.f,0.f,0.f,0.f,0.f,0.f};
  #pragma unroll
  for (int c = 0; c < 4; ++c){
    float wv[16];
    #pragma unroll
    for (int j = 0; j < 16; ++j) wv[j] = w[(c*16 + j)*HID + lane];
    #pragma unroll
    for (int r = 0; r < 8; ++r)
      #pragma unroll
      for (int j = 0; j < 16; ++j)
        acc[r] = fmaf(xl[wave][r][c*16 + j], wv[j], acc[r]);
  }
  #pragma unroll
  for (int r = 0; r < 8; ++r){
    h2preH[(size_t)(rb+r)*HID + lane] = __float2half(acc[r]);
    xl[wave][r][lane] = acc[r];
  }
  int rr = lane >> 3, t = lane & 7;
  float vs = 0.f, vd = 0.f;
  #pragma unroll
  for (int i = 0; i < 8; ++i){
    float v = xl[wave][rr][t + 8*i];
    vs = fmaf(v, asl[t + 8*i], vs);
    vd = fmaf(v, adl[t + 8*i], vd);
  }
  #pragma unroll
  for (int o = 1; o < 8; o <<= 1){
    vs += __shfl_xor(vs, o, 64);
    vd += __shfl_xor(vd, o, 64);
  }
  if (t == 0){ as_[rb + rr] = vs; ad_[rb + rr] = vd; }
}

template<int MF32>
__global__ __launch_bounds__(256, 4) void k_sage_dense(const __half* __restrict__ meanH,
                                                       const float* meanF,
                                                       const __half* __restrict__ h2H,
                                                       const float* __restrict__ wlh,
                                                       const float* __restrict__ wrh,
                                                       const float* __restrict__ b,
                                                       float* out){
  __shared__ float ml[4][8][HID];
  __shared__ float hl[4][8][HID];
  const int wave = threadIdx.x >> 6, lane = threadIdx.x & 63;
  int rb = blockIdx.x*32 + wave*8;
  if (rb >= NN) return;
  float bl = b[lane];
  #pragma unroll
  for (int r = 0; r < 8; ++r){
    if constexpr (MF32 == 1)
      ml[wave][r][lane] = meanF[(size_t)(rb+r)*HID + lane];
    else
      ml[wave][r][lane] = __half2float(meanH[(size_t)(rb+r)*HID + lane]);
    hl[wave][r][lane] = __half2float(h2H[(size_t)(rb+r)*HID + lane]);
  }
  float acc[8] = {bl,bl,bl,bl,bl,bl,bl,bl};
  #pragma unroll
  for (int c = 0; c < 4; ++c){
    float wvl[16], wvr[16];
    #pragma unroll
    for (int j = 0; j < 16; ++j){
      wvl[j] = wlh[(c*16 + j)*HID + lane];
      wvr[j] = wrh[(c*16 + j)*HID + lane];
    }
    #pragma unroll
    for (int r = 0; r < 8; ++r)
      #pragma unroll
      for (int j = 0; j < 16; ++j){
        acc[r] = fmaf(ml[wave][r][c*16 + j], wvl[j], acc[r]);
        acc[r] = fmaf(hl[wave][r][c*16 + j], wvr[j], acc[r]);
      }
  }
  #pragma unroll
  for (int r = 0; r < 8; ++r)
    out[(size_t)(rb+r)*HID + lane] = acc[r];
}

// ---------------- gathers: DUAL-NODE per wave (round-13 best), fp16 rows -----
// off[] = segment starts; n0 (even) and n0+1 share a 512-node bucket, so
// off[n0+1] is n0's end; n0+1's end = off[n0+1] + cnt[n0+1] (gapped buckets).

__device__ __forceinline__ void row_acc(const uint2* __restrict__ rh,
                                        size_t s, int f, float p, float4& acc){
  float4 r = up4(rh[s*16 + f]);
  acc.x = fmaf(r.x, p, acc.x); acc.y = fmaf(r.y, p, acc.y);
  acc.z = fmaf(r.z, p, acc.z); acc.w = fmaf(r.w, p, acc.w);
}

__global__ __launch_bounds__(256) void k_gcn_gather(const int* __restrict__ csr,
                                                    const int* __restrict__ off,
                                                    const int* __restrict__ cnt,
                                                    const uint2* __restrict__ hsH,
                                                    const float* __restrict__ dinv,
                                                    const float4* __restrict__ gcn_b4,
                                                    uint2* __restrict__ h1H){
  const int wave = threadIdx.x >> 6, lane = threadIdx.x & 63;
  int n0 = blockIdx.x*8 + wave*2, n1 = n0 + 1;
  int q = lane >> 4, f = lane & 15;
  int b0 = off[n0], e0_ = off[n0+1];
  int b1 = e0_,     e1_ = b1 + cnt[n1];
  float4 A0 = {0,0,0,0}, A1 = {0,0,0,0};
  int c0 = b0, c1 = b1;
  while (c0 < e0_ || c1 < e1_){
    int m0 = e0_ - c0; if (m0 > 64) m0 = 64;
    int m1 = e1_ - c1; if (m1 > 64) m1 = 64;
    int i0 = (lane < m0) ? csr[c0 + lane] : 0;
    int i1 = (lane < m1) ? csr[c1 + lane] : 0;
    int mm = m0 > m1 ? m0 : m1;
    for (int k = 0; k < mm; k += 16){
      int ka = k + q, kb = k + 4 + q, kc = k + 8 + q, kd = k + 12 + q;
      int s0a = __shfl(i0, ka, 64), s1a = __shfl(i1, ka, 64);
      int s0b = __shfl(i0, kb, 64), s1b = __shfl(i1, kb, 64);
      int s0c = __shfl(i0, kc, 64), s1c = __shfl(i1, kc, 64);
      int s0d = __shfl(i0, kd, 64), s1d = __shfl(i1, kd, 64);
      if (ka < m0) row_acc(hsH, (size_t)s0a, f, 1.f, A0);
      if (ka < m1) row_acc(hsH, (size_t)s1a, f, 1.f, A1);
      if (kb < m0) row_acc(hsH, (size_t)s0b, f, 1.f, A0);
      if (kb < m1) row_acc(hsH, (size_t)s1b, f, 1.f, A1);
      if (kc < m0) row_acc(hsH, (size_t)s0c, f, 1.f, A0);
      if (kc < m1) row_acc(hsH, (size_t)s1c, f, 1.f, A1);
      if (kd < m0) row_acc(hsH, (size_t)s0d, f, 1.f, A0);
      if (kd < m1) row_acc(hsH, (size_t)s1d, f, 1.f, A1);
    }
    c0 += 64; c1 += 64;
  }
  #pragma unroll
  for (int o = 16; o <= 32; o <<= 1){
    A0.x += __shfl_xor(A0.x, o, 64); A1.x += __shfl_xor(A1.x, o, 64);
    A0.y += __shfl_xor(A0.y, o, 64); A1.y += __shfl_xor(A1.y, o, 64);
    A0.z += __shfl_xor(A0.z, o, 64); A1.z += __shfl_xor(A1.z, o, 64);
    A0.w += __shfl_xor(A0.w, o, 64); A1.w += __shfl_xor(A1.w, o, 64);
  }
  if (q < 2){
    int node = q ? n1 : n0;
    float4 A = q ? A1 : A0;
    float4 s  = up4(hsH[(size_t)node*16 + f]);
    float  di = dinv[node];
    float4 b4 = gcn_b4[f];
    float4 o;
    o.x = fmaxf((A.x + s.x)*di + b4.x, 0.f);
    o.y = fmaxf((A.y + s.y)*di + b4.y, 0.f);
    o.z = fmaxf((A.z + s.z)*di + b4.z, 0.f);
    o.w = fmaxf((A.w + s.w)*di + b4.w, 0.f);
    h1H[(size_t)node*16 + f] = pk4(o);
  }
}

__global__ __launch_bounds__(256) void k_gat_gather(const int* __restrict__ csr,
                                                    const int* __restrict__ off,
                                                    const int* __restrict__ cnt,
                                                    const float* __restrict__ as_,
                                                    const float* __restrict__ ad_,
                                                    const uint2* __restrict__ h2preH,
                                                    const float4* __restrict__ gat_b4,
                                                    uint2* __restrict__ h2H){
  const int wave = threadIdx.x >> 6, lane = threadIdx.x & 63;
  int n0 = blockIdx.x*8 + wave*2, n1 = n0 + 1;
  int q = lane >> 4, f = lane & 15;
  int b0 = off[n0], e0_ = off[n0+1];
  int b1 = e0_,     e1_ = b1 + cnt[n1];
  float adi0 = ad_[n0], adi1 = ad_[n1];
  float ps0 = expf(fminf(lrelu(as_[n0] + adi0), 80.f));
  float ps1 = expf(fminf(lrelu(as_[n1] + adi1), 80.f));
  float S0 = 0.f, S1 = 0.f;
  float4 A0 = {0,0,0,0}, A1 = {0,0,0,0};
  int c0 = b0, c1 = b1;
  while (c0 < e0_ || c1 < e1_){
    int m0 = e0_ - c0; if (m0 > 64) m0 = 64;
    int m1 = e1_ - c1; if (m1 > 64) m1 = 64;
    int i0 = 0, i1 = 0; float p0 = 0.f, p1 = 0.f;
    if (lane < m0){ i0 = csr[c0 + lane]; p0 = expf(fminf(lrelu(as_[i0] + adi0), 80.f)); }
    if (lane < m1){ i1 = csr[c1 + lane]; p1 = expf(fminf(lrelu(as_[i1] + adi1), 80.f)); }
    int mm = m0 > m1 ? m0 : m1;
    for (int k = 0; k < mm; k += 16){
      int ka = k + q, kb = k + 4 + q, kc = k + 8 + q, kd = k + 12 + q;
      int s0a = __shfl(i0, ka, 64); float w0a = __shfl(p0, ka, 64);
      int s1a = __shfl(i1, ka, 64); float w1a = __shfl(p1, ka, 64);
      int s0b = __shfl(i0, kb, 64); float w0b = __shfl(p0, kb, 64);
      int s1b = __shfl(i1, kb, 64); float w1b = __shfl(p1, kb, 64);
      int s0c = __shfl(i0, kc, 64); float w0c = __shfl(p0, kc, 64);
      int s1c = __shfl(i1, kc, 64); float w1c = __shfl(p1, kc, 64);
      int s0d = __shfl(i0, kd, 64); float w0d = __shfl(p0, kd, 64);
      int s1d = __shfl(i1, kd, 64); float w1d = __shfl(p1, kd, 64);
      if (ka < m0){ row_acc(h2preH, (size_t)s0a, f, w0a, A0); S0 += w0a; }
      if (ka < m1){ row_acc(h2preH, (size_t)s1a, f, w1a, A1); S1 += w1a; }
      if (kb < m0){ row_acc(h2preH, (size_t)s0b, f, w0b, A0); S0 += w0b; }
      if (kb < m1){ row_acc(h2preH, (size_t)s1b, f, w1b, A1); S1 += w1b; }
      if (kc < m0){ row_acc(h2preH, (size_t)s0c, f, w0c, A0); S0 += w0c; }
      if (kc < m1){ row_acc(h2preH, (size_t)s1c, f, w1c, A1); S1 += w1c; }
      if (kd < m0){ row_acc(h2preH, (size_t)s0d, f, w0d, A0); S0 += w0d; }
      if (kd < m1){ row_acc(h2preH, (size_t)s1d, f, w1d, A1); S1 += w1d; }
    }
    c0 += 64; c1 += 64;
  }
  #pragma unroll
  for (int o = 16; o <= 32; o <<= 1){
    A0.x += __shfl_xor(A0.x, o, 64); A1.x += __shfl_xor(A1.x, o, 64);
    A0.y += __shfl_xor(A0.y, o, 64); A1.y += __shfl_xor(A1.y, o, 64);
    A0.z += __shfl_xor(A0.z, o, 64); A1.z += __shfl_xor(A1.z, o, 64);
    A0.w += __shfl_xor(A0.w, o, 64); A1.w += __shfl_xor(A1.w, o, 64);
    S0   += __shfl_xor(S0,   o, 64); S1   += __shfl_xor(S1,   o, 64);
  }
  if (q < 2){
    int node = q ? n1 : n0;
    float4 A = q ? A1 : A0;
    float ps = q ? ps1 : ps0;
    float inv = 1.f/((q ? S1 : S0) + ps);
    float4 h0 = up4(h2preH[(size_t)node*16 + f]);
    float4 b4 = gat_b4[f];
    float4 o;
    o.x = fmaxf((A.x + h0.x*ps)*inv + b4.x, 0.f);
    o.y = fmaxf((A.y + h0.y*ps)*inv + b4.y, 0.f);
    o.z = fmaxf((A.z + h0.z*ps)*inv + b4.z, 0.f);
    o.w = fmaxf((A.w + h0.w*ps)*inv + b4.w, 0.f);
    h2H[(size_t)node*16 + f] = pk4(o);
  }
}

template<int MF32>
__global__ __launch_bounds__(256) void k_sage_gather(const int* __restrict__ csr,
                                                     const int* __restrict__ off,
                                                     const int* __restrict__ cnt,
                                                     const uint2* __restrict__ h2H,
                                                     uint2* __restrict__ meanH,
                                                     float4* meanF){
  const int wave = threadIdx.x >> 6, lane = threadIdx.x & 63;
  int n0 = blockIdx.x*8 + wave*2, n1 = n0 + 1;
  int q = lane >> 4, f = lane & 15;
  int b0 = off[n0], e0_ = off[n0+1];
  int b1 = e0_,     e1_ = b1 + cnt[n1];
  float4 A0 = {0,0,0,0}, A1 = {0,0,0,0};
  int c0 = b0, c1 = b1;
  while (c0 < e0_ || c1 < e1_){
    int m0 = e0_ - c0; if (m0 > 64) m0 = 64;
    int m1 = e1_ - c1; if (m1 > 64) m1 = 64;
    int i0 = (lane < m0) ? csr[c0 + lane] : 0;
    int i1 = (lane < m1) ? csr[c1 + lane] : 0;
    int mm = m0 > m1 ? m0 : m1;
    for (int k = 0; k < mm; k += 16){
      int ka = k + q, kb = k + 4 + q, kc = k + 8 + q, kd = k + 12 + q;
      int s0a = __shfl(i0, ka, 64), s1a = __shfl(i1, ka, 64);
      int s0b = __shfl(i0, kb, 64), s1b = __shfl(i1, kb, 64);
      int s0c = __shfl(i0, kc, 64), s1c = __shfl(i1, kc, 64);
      int s0d = __shfl(i0, kd, 64), s1d = __shfl(i1, kd, 64);
      if (ka < m0) row_acc(h2H, (size_t)s0a, f, 1.f, A0);
      if (ka < m1) row_acc(h2H, (size_t)s1a, f, 1.f, A1);
      if (kb < m0) row_acc(h2H, (size_t)s0b, f, 1.f, A0);
      if (kb < m1) row_acc(h2H, (size_t)s1b, f, 1.f, A1);
      if (kc < m0) row_acc(h2H, (size_t)s0c, f, 1.f, A0);
      if (kc < m1) row_acc(h2H, (size_t)s1c, f, 1.f, A1);
      if (kd < m0) row_acc(h2H, (size_t)s0d, f, 1.f, A0);
      if (kd < m1) row_acc(h2H, (size_t)s1d, f, 1.f, A1);
    }
    c0 += 64; c1 += 64;
  }
  #pragma unroll
  for (int o = 16; o <= 32; o <<= 1){
    A0.x += __shfl_xor(A0.x, o, 64); A1.x += __shfl_xor(A1.x, o, 64);
    A0.y += __shfl_xor(A0.y, o, 64); A1.y += __shfl_xor(A1.y, o, 64);
    A0.z += __shfl_xor(A0.z, o, 64); A1.z += __shfl_xor(A1.z, o, 64);
    A0.w += __shfl_xor(A0.w, o, 64); A1.w += __shfl_xor(A1.w, o, 64);
  }
  if (q < 2){
    int node = q ? n1 : n0;
    float4 A = q ? A1 : A0;
    float inv = 1.f/fmaxf((float)cnt[node], 1.f);
    float4 o = {A.x*inv, A.y*inv, A.z*inv, A.w*inv};
    if constexpr (MF32 == 1) meanF[(size_t)node*16 + f] = o;
    else                     meanH[(size_t)node*16 + f] = pk4(o);
  }
}

// ---------------- launch ----------------

extern "C" void kernel_launch(void* const* d_in, const int* in_sizes, int n_in,
                              void* d_out, int out_size, void* d_ws, size_t ws_size,
                              hipStream_t stream) {
  const float* x      = (const float*)d_in[0];
  const int*   ei     = (const int*)d_in[1];
  const int*   src    = ei;
  const int*   dstp   = ei + NE;
  const float* gcn_w  = (const float*)d_in[2];
  const float* gcn_b  = (const float*)d_in[3];
  const float* gat_w  = (const float*)d_in[4];
  const float* att_s  = (const float*)d_in[5];
  const float* att_d  = (const float*)d_in[6];
  const float* gat_b  = (const float*)d_in[7];
  const float* s_wl   = (const float*)d_in[8];
  const float* s_wr   = (const float*)d_in[9];
  const float* s_b    = (const float*)d_in[10];
  float* outp = (float*)d_out;

  // workspace layout (4-byte words)
  int*   cur   = (int*)d_ws;             // 256 (196 used)
  int*   cnt   = cur + 256;              // NN
  int*   off   = cnt + NN;               // NN (+pad)
  float* dinv  = (float*)(off + NN + 8);
  float* as_   = dinv + NN;
  float* ad_   = as_  + NN;
  unsigned* bucketed = (unsigned*)(ad_ + NN);   // NBUK*CAP
  int*   csr   = (int*)(bucketed + (size_t)NBUK*CAP);  // NBUK*CAP (gapped)

  // fp16 planes: 256-byte aligned (round-12 lesson: misaligned 128B rows cost
  // +50% FETCH in the gathers)
  size_t hb_off = (((size_t)(char*)(csr + (size_t)NBUK*CAP) - (size_t)(char*)d_ws)
                   + 255) & ~(size_t)255;
  __half* HB0 = (__half*)((char*)d_ws + hb_off);
  __half* HB1 = HB0 + (size_t)NN*HID;

  const size_t NH = (size_t)NN*HID;
  size_t need  = hb_off + 2*NH*2;
  size_t need1 = hb_off + NH*2;

  const int B = 256;
  const int GROWS = (NN + 31)/32;
  const int GG2 = NN/8;                 // dual-node gathers: 12500 blocks exact
  const int GA = (NE + ACH - 1)/ACH;

  // CSR build: fixed-capacity buckets (no pre-count, no scan)
  k_init_cur<<<1, 256, 0, stream>>>(cur);
  kA1       <<<GA, B, 0, stream>>>(src, dstp, cur, bucketed);
  kB        <<<NBUK, 256, 0, stream>>>(bucketed, cur, csr, off, cnt, dinv);

  if (ws_size >= need){
    // buf0: hs -> h2pre -> mean ; buf1: h1 -> h2
    k_gemm_in   <<<GROWS, B, 0, stream>>>(x, gcn_w, dinv, HB0);
    k_gcn_gather<<<GG2, B, 0, stream>>>(csr, off, cnt, (const uint2*)HB0, dinv,
                                        (const float4*)gcn_b, (uint2*)HB1);
    k_gat_lin   <<<GROWS, B, 0, stream>>>(HB1, gat_w, att_s, att_d, HB0, as_, ad_);
    k_gat_gather<<<GG2, B, 0, stream>>>(csr, off, cnt, as_, ad_, (const uint2*)HB0,
                                        (const float4*)gat_b, (uint2*)HB1);
    k_sage_gather<0><<<GG2, B, 0, stream>>>(csr, off, cnt, (const uint2*)HB1,
                                            (uint2*)HB0, nullptr);
    k_sage_dense<0><<<GROWS, B, 0, stream>>>(HB0, nullptr, HB1,
                                             s_wl, s_wr, s_b, outp);
  } else {
    __half* F0 = (ws_size >= need1) ? (__half*)outp : HB0;
    __half* F1 = (ws_size >= need1) ? HB0 : (__half*)outp;
    k_gemm_in   <<<GROWS, B, 0, stream>>>(x, gcn_w, dinv, F0);
    k_gcn_gather<<<GG2, B, 0, stream>>>(csr, off, cnt, (const uint2*)F0, dinv,
                                        (const float4*)gcn_b, (uint2*)F1);
    k_gat_lin   <<<GROWS, B, 0, stream>>>(F1, gat_w, att_s, att_d, F0, as_, ad_);
    k_gat_gather<<<GG2, B, 0, stream>>>(csr, off, cnt, as_, ad_, (const uint2*)F0,
                                        (const float4*)gat_b, (uint2*)F1);
    k_sage_gather<1><<<GG2, B, 0, stream>>>(csr, off, cnt, (const uint2*)F1,
                                            nullptr, (float4*)outp);
    k_sage_dense<1><<<GROWS, B, 0, stream>>>(nullptr, outp, F1,
                                             s_wl, s_wr, s_b, outp);
  }
}